// Round 22
// baseline (192.241 us; speedup 1.0000x reference)
//
#include <hip/hip_runtime.h>

#define NN 50000
#define HID 64
#define NE 800000
#define NP 100000
#define BN_EPS 1e-5f
#define NB1 196   // ceil(NN/256)
#define MAXDEG 96 // static CSR segment stride; P(deg>96)~1e-16 for Poisson(16)

static inline size_t alignup(size_t x) { return (x + 255) & ~(size_t)255; }

typedef __attribute__((ext_vector_type(8))) short bf16x8;  // 8 bf16 (4 VGPRs)
typedef __attribute__((ext_vector_type(4))) float f32x4;   // MFMA 16x16 accumulator

__device__ __forceinline__ void f4fma(float a, const float4& w, float4& c) {
    c.x += a * w.x; c.y += a * w.y; c.z += a * w.z; c.w += a * w.w;
}
__device__ __forceinline__ void f4add(const float4& a, float4& c) {
    c.x += a.x; c.y += a.y; c.z += a.z; c.w += a.w;
}
__device__ __forceinline__ unsigned bfpack(float a, float b) {
    unsigned ua = __float_as_uint(a), ub = __float_as_uint(b);
    ua = (ua + 0x7fffu + ((ua >> 16) & 1u)) >> 16;
    ub = (ub + 0x7fffu + ((ub >> 16) & 1u)) >> 16;
    return ua | (ub << 16);
}
__device__ __forceinline__ unsigned short bf1(float a) {
    unsigned ua = __float_as_uint(a);
    return (unsigned short)((ua + 0x7fffu + ((ua >> 16) & 1u)) >> 16);
}
__device__ __forceinline__ float4 bf2f4(uint2 u) {
    float4 r;
    r.x = __uint_as_float(u.x << 16);
    r.y = __uint_as_float(u.x & 0xffff0000u);
    r.z = __uint_as_float(u.y << 16);
    r.w = __uint_as_float(u.y & 0xffff0000u);
    return r;
}

// ---------- zero cnt + BN sums ----------

__global__ __launch_bounds__(256) void k_zero(int* __restrict__ cnt, float* __restrict__ sums) {
    int i = blockIdx.x * blockDim.x + threadIdx.x;
    if (i < NN) cnt[i] = 0;
    if (i < 256) sums[i] = 0.f;
}

// ---------- degree count + per-edge rank (byte) ----------

__global__ __launch_bounds__(256) void k_count(const int* __restrict__ col,
                                               int* __restrict__ cnt, unsigned char* __restrict__ rank) {
    int e = blockIdx.x * blockDim.x + threadIdx.x;
    if (e < NE) rank[e] = (unsigned char)atomicAdd(&cnt[col[e]], 1);
}

// ---------- CSR fill: static segments at col*MAXDEG, single 2B store per edge ----------

__global__ __launch_bounds__(256) void k_fill(const int* __restrict__ row, const int* __restrict__ col,
                                              const unsigned char* __restrict__ rank,
                                              unsigned short* __restrict__ csr) {
    int e = blockIdx.x * blockDim.x + threadIdx.x;
    if (e >= NE) return;
    csr[col[e] * MAXDEG + (int)rank[e]] = (unsigned short)row[e];
}

// ---------- input projection: 32 nodes/block, bf16 W + bf16 A in LDS (~24.7KB) ----------
// x = concat(id,n2v) @ W + b ; xh = bf16(dis * x), dis = rsqrt(cnt+1) inline

__global__ __launch_bounds__(256) void k_proj(const float* __restrict__ id_emb,
                                              const float* __restrict__ n2v,
                                              const float* __restrict__ W,
                                              const float* __restrict__ b,
                                              const int* __restrict__ cnt,
                                              float* __restrict__ x,
                                              unsigned short* __restrict__ xh) {
    __shared__ unsigned short Wlh[128 * 64];   // 16 KB
    __shared__ unsigned short Al[32 * 132];    // 8.45 KB
    int tid = threadIdx.x;
    int node0 = blockIdx.x * 32;
    const float2* W2f = (const float2*)W;
#pragma unroll
    for (int it = 0; it < 16; ++it) {
        int i = it * 256 + tid;
        float2 w = W2f[i];
        *(unsigned*)&Wlh[2 * i] = bfpack(w.x, w.y);
    }
    const float2* id2 = (const float2*)id_emb;
    const float2* nv2 = (const float2*)n2v;
#pragma unroll
    for (int it = 0; it < 8; ++it) {
        int i = it * 256 + tid;
        int r = i >> 6, kp = i & 63;
        int n = node0 + r;
        float2 v = make_float2(0.f, 0.f);
        if (n < NN) v = (kp < 32) ? id2[n * 32 + kp] : nv2[n * 32 + (kp - 32)];
        *(unsigned*)&Al[r * 132 + 2 * kp] = bfpack(v.x, v.y);
    }
    __syncthreads();
    int sub = tid >> 4, q = tid & 15;          // rows sub*2..+1, cols 4q..4q+3
    const uint2* W2 = (const uint2*)Wlh;
    float4* x4 = (float4*)x;
    uint2* xh2 = (uint2*)xh;
    float4 bb = ((const float4*)b)[q];
    float4 c0 = bb, c1 = bb;
#pragma unroll 4
    for (int k4 = 0; k4 < 32; ++k4) {
        float4 w0 = bf2f4(W2[(k4 * 4 + 0) * 16 + q]);
        float4 w1 = bf2f4(W2[(k4 * 4 + 1) * 16 + q]);
        float4 w2 = bf2f4(W2[(k4 * 4 + 2) * 16 + q]);
        float4 w3 = bf2f4(W2[(k4 * 4 + 3) * 16 + q]);
        float4 a0 = bf2f4(*(const uint2*)&Al[(sub * 2 + 0) * 132 + k4 * 4]);
        float4 a1 = bf2f4(*(const uint2*)&Al[(sub * 2 + 1) * 132 + k4 * 4]);
        f4fma(a0.x, w0, c0); f4fma(a0.y, w1, c0); f4fma(a0.z, w2, c0); f4fma(a0.w, w3, c0);
        f4fma(a1.x, w0, c1); f4fma(a1.y, w1, c1); f4fma(a1.z, w2, c1); f4fma(a1.w, w3, c1);
    }
    int n0 = node0 + sub * 2;
    if (n0 + 0 < NN) { float d = rsqrtf((float)(cnt[n0+0] + 1)); x4[(n0+0)*16+q] = c0;
        xh2[(n0+0)*16+q] = make_uint2(bfpack(c0.x*d,c0.y*d), bfpack(c0.z*d,c0.w*d)); }
    if (n0 + 1 < NN) { float d = rsqrtf((float)(cnt[n0+1] + 1)); x4[(n0+1)*16+q] = c1;
        xh2[(n0+1)*16+q] = make_uint2(bfpack(c1.x*d,c1.y*d), bfpack(c1.z*d,c1.w*d)); }
}

// ---------- standalone CSR gather: zero LDS, high occupancy, uint4 index loads ----------
// th[d] = bf16( dis[d] * (sum_j xh[src_j] + xh[d]) )   with xh = dis*x prescaled

__global__ __launch_bounds__(256) void k_gather(const int* __restrict__ cnt,
                                                const unsigned short* __restrict__ csr,
                                                const unsigned short* __restrict__ xh,
                                                unsigned short* __restrict__ th) {
    int gw = (blockIdx.x * blockDim.x + threadIdx.x) >> 6;
    int lane = threadIdx.x & 63;
    int sub = lane >> 4, q = lane & 15;
    int node = gw * 4 + sub;
    if (node >= NN) return;
    const uint2* xh2 = (const uint2*)xh;
    float4 acc = make_float4(0.f, 0.f, 0.f, 0.f);
    const unsigned short* cs = csr + node * MAXDEG;   // 16B-aligned static segment
    int c = cnt[node];
    int jj = 0;
    for (; jj + 7 < c; jj += 8) {
        uint4 s8 = *(const uint4*)(cs + jj);
        int s0 = s8.x & 0xffff, s1 = s8.x >> 16;
        int s2 = s8.y & 0xffff, s3 = s8.y >> 16;
        int s4 = s8.z & 0xffff, s5 = s8.z >> 16;
        int s6 = s8.w & 0xffff, s7 = s8.w >> 16;
        uint2 u0 = xh2[s0 * 16 + q];
        uint2 u1 = xh2[s1 * 16 + q];
        uint2 u2 = xh2[s2 * 16 + q];
        uint2 u3 = xh2[s3 * 16 + q];
        uint2 u4 = xh2[s4 * 16 + q];
        uint2 u5 = xh2[s5 * 16 + q];
        uint2 u6 = xh2[s6 * 16 + q];
        uint2 u7 = xh2[s7 * 16 + q];
        f4add(bf2f4(u0), acc); f4add(bf2f4(u1), acc);
        f4add(bf2f4(u2), acc); f4add(bf2f4(u3), acc);
        f4add(bf2f4(u4), acc); f4add(bf2f4(u5), acc);
        f4add(bf2f4(u6), acc); f4add(bf2f4(u7), acc);
    }
    for (; jj < c; ++jj) {
        uint2 u0 = xh2[cs[jj] * 16 + q];
        f4add(bf2f4(u0), acc);
    }
    f4add(bf2f4(xh2[node * 16 + q]), acc);   // self term (xh prescaled)
    float di = rsqrtf((float)(c + 1));
    acc.x *= di; acc.y *= di; acc.z *= di; acc.w *= di;
    ((uint2*)th)[node * 16 + q] = make_uint2(bfpack(acc.x, acc.y), bfpack(acc.z, acc.w));
}

// ---------- MFMA conv GEMM + BN stats: agg(bf16) = th @ W ----------
// 4 waves/block, wave = 16-node x 64-dim tile via 8x mfma_f32_16x16x32_bf16.
// A frag: lane l -> row l%16, k = (l>>4)*8 + [0..7] (+32 for K-half 1), contiguous bf16x8 from th.
// B frag: lane l -> col l%16, same k pattern, from LDS W^T (bf16, row-padded to 72).
// C/D: col = lane&15, row = (lane>>4)*4 + reg  [verified mapping].

__global__ __launch_bounds__(256) void k_gemm_stats(const unsigned short* __restrict__ th,
                                                    const float* __restrict__ W,
                                                    unsigned short* __restrict__ agg,
                                                    float* __restrict__ sums) {
    __shared__ unsigned short Wt[64 * 72];   // W^T bf16, pad 72 (9.2 KB)
    __shared__ float ls0[4][64];
    __shared__ float ls1[4][64];
    int tid = threadIdx.x;
    // stage W^T: Wt[n][k] = bf16(W[k*64+n]); read coalesced (i = k*64+n)
#pragma unroll
    for (int it = 0; it < 16; ++it) {
        int i = it * 256 + tid;
        int k = i >> 6, n = i & 63;
        Wt[n * 72 + k] = bf1(W[i]);
    }
    __syncthreads();
    int wave = tid >> 6, lane = tid & 63;
    int n0w = blockIdx.x * 64 + wave * 16;
    int arow = lane & 15;
    int kgrp = lane >> 4;                     // 0..3
    int anode = min(n0w + arow, NN - 1);
    const bf16x8* thv = (const bf16x8*)th;    // th row = 8 units of 8 bf16
    bf16x8 a0 = thv[anode * 8 + kgrp];        // k 0..31
    bf16x8 a1 = thv[anode * 8 + 4 + kgrp];    // k 32..63
    const bf16x8* wtv = (const bf16x8*)Wt;    // Wt row = 9 units (72 shorts)
    f32x4 acc[4];
#pragma unroll
    for (int ct = 0; ct < 4; ++ct) {
        int bro = (ct * 16 + arow) * 9;
        bf16x8 b0 = wtv[bro + kgrp];
        bf16x8 b1 = wtv[bro + 4 + kgrp];
        f32x4 c = {0.f, 0.f, 0.f, 0.f};
        c = __builtin_amdgcn_mfma_f32_16x16x32_bf16(a0, b0, c, 0, 0, 0);
        c = __builtin_amdgcn_mfma_f32_16x16x32_bf16(a1, b1, c, 0, 0, 0);
        acc[ct] = c;
    }
    // store agg (bf16) + column stats (guard tail rows)
#pragma unroll
    for (int ct = 0; ct < 4; ++ct) {
        float p1 = 0.f, p2 = 0.f;
#pragma unroll
        for (int j = 0; j < 4; ++j) {
            int node = n0w + kgrp * 4 + j;    // C/D row = (lane>>4)*4 + j
            float v = acc[ct][j];
            if (node < NN) {
                agg[node * 64 + ct * 16 + arow] = bf1(v);
                p1 += v;
                p2 += v * v;
            }
        }
        p1 += __shfl_xor(p1, 16); p2 += __shfl_xor(p2, 16);
        p1 += __shfl_xor(p1, 32); p2 += __shfl_xor(p2, 32);
        if (kgrp == 0) { ls0[wave][ct * 16 + arow] = p1; ls1[wave][ct * 16 + arow] = p2; }
    }
    __syncthreads();
    if (tid < 64) {
        float a = ls0[0][tid] + ls0[1][tid] + ls0[2][tid] + ls0[3][tid];
        atomicAdd(&sums[tid], a);
    } else if (tid < 128) {
        int c = tid - 64;
        float a = ls1[0][c] + ls1[1][c] + ls1[2][c] + ls1[3][c];
        atomicAdd(&sums[64 + c], a);
    }
}

// ---------- x += relu(BN(agg)); refresh bf16 mirror ----------
// prescale==1: write x and prescaled xh (mid layer). prescale==0 (final): write ONLY xh (x dead).

__global__ __launch_bounds__(256) void k_bnupdate(const unsigned short* __restrict__ agg,
                                                  const float* __restrict__ sums,
                                                  const float* __restrict__ gamma,
                                                  const float* __restrict__ beta,
                                                  const int* __restrict__ cnt,
                                                  int prescale,
                                                  float* __restrict__ x,
                                                  unsigned short* __restrict__ xh) {
    int i = blockIdx.x * blockDim.x + threadIdx.x;
    if (i >= NN * 16) return;
    int f4 = i & 15;
    const float invn = 1.0f / (float)NN;
    float4 sm = ((const float4*)sums)[f4];
    float4 sq = ((const float4*)(sums + 64))[f4];
    float4 g = ((const float4*)gamma)[f4];
    float4 be = ((const float4*)beta)[f4];
    float4 a = bf2f4(((const uint2*)agg)[i]);
    float4 xv = ((const float4*)x)[i];
    float mu, var, rstd, xn;
    mu = sm.x * invn; var = sq.x * invn - mu * mu; rstd = rsqrtf(var + BN_EPS);
    xn = (a.x - mu) * rstd * g.x + be.x; xv.x += fmaxf(xn, 0.f);
    mu = sm.y * invn; var = sq.y * invn - mu * mu; rstd = rsqrtf(var + BN_EPS);
    xn = (a.y - mu) * rstd * g.y + be.y; xv.y += fmaxf(xn, 0.f);
    mu = sm.z * invn; var = sq.z * invn - mu * mu; rstd = rsqrtf(var + BN_EPS);
    xn = (a.z - mu) * rstd * g.z + be.z; xv.z += fmaxf(xn, 0.f);
    mu = sm.w * invn; var = sq.w * invn - mu * mu; rstd = rsqrtf(var + BN_EPS);
    xn = (a.w - mu) * rstd * g.w + be.w; xv.w += fmaxf(xn, 0.f);
    if (prescale) {
        ((float4*)x)[i] = xv;
        float d = rsqrtf((float)(cnt[i >> 4] + 1));
        ((uint2*)xh)[i] = make_uint2(bfpack(xv.x * d, xv.y * d), bfpack(xv.z * d, xv.w * d));
    } else {
        ((uint2*)xh)[i] = make_uint2(bfpack(xv.x, xv.y), bfpack(xv.z, xv.w));
    }
}

// ---------- decoder (bf16 rows, 4 edges/wave) ----------

__global__ __launch_bounds__(256) void k_decode(const int* __restrict__ pred,
                                                const unsigned short* __restrict__ zh,
                                                float* __restrict__ out) {
    int gw = (blockIdx.x * blockDim.x + threadIdx.x) >> 6;
    int lane = threadIdx.x & 63;
    int sub = lane >> 4, q = lane & 15;
    int p = gw * 4 + sub;
    if (p >= NP) return;
    const uint2* z2 = (const uint2*)zh;
    int a = pred[2 * p], b = pred[2 * p + 1];
    float4 va = bf2f4(z2[a * 16 + q]);
    float4 vb = bf2f4(z2[b * 16 + q]);
    float v = va.x * vb.x + va.y * vb.y + va.z * vb.z + va.w * vb.w;
    v += __shfl_xor(v, 1);
    v += __shfl_xor(v, 2);
    v += __shfl_xor(v, 4);
    v += __shfl_xor(v, 8);
    if (q == 0) out[p] = v;
}

extern "C" void kernel_launch(void* const* d_in, const int* in_sizes, int n_in,
                              void* d_out, int out_size, void* d_ws, size_t ws_size,
                              hipStream_t stream) {
    const int* edge_index = (const int*)d_in[0];   // [2][NE]
    const int* pred       = (const int*)d_in[1];   // [NP][2]
    const float* id_emb   = (const float*)d_in[2];
    const float* n2v      = (const float*)d_in[3];
    const float* proj_w   = (const float*)d_in[4];
    const float* proj_b   = (const float*)d_in[5];
    const float* conv_w   = (const float*)d_in[6]; // [2][64][64]
    // d_in[7] conv_b cancels inside BatchNorm -> skipped
    const float* gamma    = (const float*)d_in[8];
    const float* beta     = (const float*)d_in[9];
    float* out = (float*)d_out;

    char* ws = (char*)d_ws;
    size_t off = 0;
    int* cnt     = (int*)(ws + off);   off += alignup(NN * 4);
    unsigned char* rank = (unsigned char*)(ws + off); off += alignup((size_t)NE);
    unsigned short* csr = (unsigned short*)(ws + off); off += alignup((size_t)NN * MAXDEG * 2);
    float* x     = (float*)(ws + off); off += alignup((size_t)NN * 64 * 4);
    unsigned short* agg = (unsigned short*)(ws + off); off += alignup((size_t)NN * 64 * 2);
    unsigned short* xh = (unsigned short*)(ws + off); off += alignup((size_t)NN * 64 * 2);
    unsigned short* th = (unsigned short*)(ws + off); off += alignup((size_t)(NN * 64 + 64) * 2);
    float* sums  = (float*)(ws + off); // 256 floats (2 layers x {sum,sumsq})

    const int* row = edge_index;
    const int* col = edge_index + NE;

    // CSR build (once, reused for both layers)
    k_zero<<<NB1, 256, 0, stream>>>(cnt, sums);
    k_count<<<(NE + 255) / 256, 256, 0, stream>>>(col, cnt, rank);
    k_fill<<<(NE + 255) / 256, 256, 0, stream>>>(row, col, rank, csr);

    k_proj<<<(NN + 31) / 32, 256, 0, stream>>>(id_emb, n2v, proj_w, proj_b, cnt, x, xh);

    for (int l = 0; l < 2; ++l) {
        k_gather<<<((NN + 3) / 4 * 64 + 255) / 256, 256, 0, stream>>>(cnt, csr, xh, th);
        k_gemm_stats<<<(NN + 63) / 64, 256, 0, stream>>>(th, conv_w + l * 64 * 64, agg, sums + l * 128);
        k_bnupdate<<<(NN * 16 + 255) / 256, 256, 0, stream>>>(agg, sums + l * 128, gamma + l * 64,
                                                              beta + l * 64, cnt, (l == 0) ? 1 : 0, x, xh);
    }

    k_decode<<<(NP / 4 * 64 + 255) / 256, 256, 0, stream>>>(pred, xh, out);
}

// Round 23
// 184.700 us; speedup vs baseline: 1.0408x; 1.0408x over previous
//
#include <hip/hip_runtime.h>

#define NN 50000
#define HID 64
#define NE 800000
#define NP 100000
#define BN_EPS 1e-5f
#define NB1 196   // ceil(NN/256)
#define MAXDEG 96 // static CSR segment stride; P(deg>96)~1e-16 for Poisson(16)

static inline size_t alignup(size_t x) { return (x + 255) & ~(size_t)255; }

__device__ __forceinline__ void f4fma(float a, const float4& w, float4& c) {
    c.x += a * w.x; c.y += a * w.y; c.z += a * w.z; c.w += a * w.w;
}
__device__ __forceinline__ void f4add(const float4& a, float4& c) {
    c.x += a.x; c.y += a.y; c.z += a.z; c.w += a.w;
}
__device__ __forceinline__ unsigned bfpack(float a, float b) {
    unsigned ua = __float_as_uint(a), ub = __float_as_uint(b);
    ua = (ua + 0x7fffu + ((ua >> 16) & 1u)) >> 16;
    ub = (ub + 0x7fffu + ((ub >> 16) & 1u)) >> 16;
    return ua | (ub << 16);
}
__device__ __forceinline__ float4 bf2f4(uint2 u) {
    float4 r;
    r.x = __uint_as_float(u.x << 16);
    r.y = __uint_as_float(u.x & 0xffff0000u);
    r.z = __uint_as_float(u.y << 16);
    r.w = __uint_as_float(u.y & 0xffff0000u);
    return r;
}

// ---------- zero cnt + BN sums ----------

__global__ __launch_bounds__(256) void k_zero(int* __restrict__ cnt, float* __restrict__ sums) {
    int i = blockIdx.x * blockDim.x + threadIdx.x;
    if (i < NN) cnt[i] = 0;
    if (i < 256) sums[i] = 0.f;
}

// ---------- degree count + per-edge rank (byte) ----------

__global__ __launch_bounds__(256) void k_count(const int* __restrict__ col,
                                               int* __restrict__ cnt, unsigned char* __restrict__ rank) {
    int e = blockIdx.x * blockDim.x + threadIdx.x;
    if (e < NE) rank[e] = (unsigned char)atomicAdd(&cnt[col[e]], 1);
}

// ---------- CSR fill: static segments at col*MAXDEG, single 2B store per edge ----------

__global__ __launch_bounds__(256) void k_fill(const int* __restrict__ row, const int* __restrict__ col,
                                              const unsigned char* __restrict__ rank,
                                              unsigned short* __restrict__ csr) {
    int e = blockIdx.x * blockDim.x + threadIdx.x;
    if (e >= NE) return;
    csr[col[e] * MAXDEG + (int)rank[e]] = (unsigned short)row[e];
}

// ---------- input projection: 32 nodes/block, bf16 W + bf16 A in LDS (~24.7KB) ----------
// x = concat(id,n2v) @ W + b ; xh = bf16(dis * x), dis = rsqrt(cnt+1) inline

__global__ __launch_bounds__(256) void k_proj(const float* __restrict__ id_emb,
                                              const float* __restrict__ n2v,
                                              const float* __restrict__ W,
                                              const float* __restrict__ b,
                                              const int* __restrict__ cnt,
                                              float* __restrict__ x,
                                              unsigned short* __restrict__ xh) {
    __shared__ unsigned short Wlh[128 * 64];   // 16 KB
    __shared__ unsigned short Al[32 * 132];    // 8.45 KB
    int tid = threadIdx.x;
    int node0 = blockIdx.x * 32;
    const float2* W2f = (const float2*)W;
#pragma unroll
    for (int it = 0; it < 16; ++it) {
        int i = it * 256 + tid;
        float2 w = W2f[i];
        *(unsigned*)&Wlh[2 * i] = bfpack(w.x, w.y);
    }
    const float2* id2 = (const float2*)id_emb;
    const float2* nv2 = (const float2*)n2v;
#pragma unroll
    for (int it = 0; it < 8; ++it) {
        int i = it * 256 + tid;
        int r = i >> 6, kp = i & 63;
        int n = node0 + r;
        float2 v = make_float2(0.f, 0.f);
        if (n < NN) v = (kp < 32) ? id2[n * 32 + kp] : nv2[n * 32 + (kp - 32)];
        *(unsigned*)&Al[r * 132 + 2 * kp] = bfpack(v.x, v.y);
    }
    __syncthreads();
    int sub = tid >> 4, q = tid & 15;          // rows sub*2..+1, cols 4q..4q+3
    const uint2* W2 = (const uint2*)Wlh;
    float4* x4 = (float4*)x;
    uint2* xh2 = (uint2*)xh;
    float4 bb = ((const float4*)b)[q];
    float4 c0 = bb, c1 = bb;
#pragma unroll 4
    for (int k4 = 0; k4 < 32; ++k4) {
        float4 w0 = bf2f4(W2[(k4 * 4 + 0) * 16 + q]);
        float4 w1 = bf2f4(W2[(k4 * 4 + 1) * 16 + q]);
        float4 w2 = bf2f4(W2[(k4 * 4 + 2) * 16 + q]);
        float4 w3 = bf2f4(W2[(k4 * 4 + 3) * 16 + q]);
        float4 a0 = bf2f4(*(const uint2*)&Al[(sub * 2 + 0) * 132 + k4 * 4]);
        float4 a1 = bf2f4(*(const uint2*)&Al[(sub * 2 + 1) * 132 + k4 * 4]);
        f4fma(a0.x, w0, c0); f4fma(a0.y, w1, c0); f4fma(a0.z, w2, c0); f4fma(a0.w, w3, c0);
        f4fma(a1.x, w0, c1); f4fma(a1.y, w1, c1); f4fma(a1.z, w2, c1); f4fma(a1.w, w3, c1);
    }
    int n0 = node0 + sub * 2;
    if (n0 + 0 < NN) { float d = rsqrtf((float)(cnt[n0+0] + 1)); x4[(n0+0)*16+q] = c0;
        xh2[(n0+0)*16+q] = make_uint2(bfpack(c0.x*d,c0.y*d), bfpack(c0.z*d,c0.w*d)); }
    if (n0 + 1 < NN) { float d = rsqrtf((float)(cnt[n0+1] + 1)); x4[(n0+1)*16+q] = c1;
        xh2[(n0+1)*16+q] = make_uint2(bfpack(c1.x*d,c1.y*d), bfpack(c1.z*d,c1.w*d)); }
}

// ---------- standalone CSR gather: zero LDS, high occupancy, uint4 index loads ----------
// th[d] = bf16( dis[d] * (sum_j xh[src_j] + xh[d]) )   with xh = dis*x prescaled

__global__ __launch_bounds__(256) void k_gather(const int* __restrict__ cnt,
                                                const unsigned short* __restrict__ csr,
                                                const unsigned short* __restrict__ xh,
                                                unsigned short* __restrict__ th) {
    int gw = (blockIdx.x * blockDim.x + threadIdx.x) >> 6;
    int lane = threadIdx.x & 63;
    int sub = lane >> 4, q = lane & 15;
    int node = gw * 4 + sub;
    if (node >= NN) return;
    const uint2* xh2 = (const uint2*)xh;
    float4 acc = make_float4(0.f, 0.f, 0.f, 0.f);
    const unsigned short* cs = csr + node * MAXDEG;   // 16B-aligned static segment
    int c = cnt[node];
    int jj = 0;
    for (; jj + 7 < c; jj += 8) {
        uint4 s8 = *(const uint4*)(cs + jj);
        int s0 = s8.x & 0xffff, s1 = s8.x >> 16;
        int s2 = s8.y & 0xffff, s3 = s8.y >> 16;
        int s4 = s8.z & 0xffff, s5 = s8.z >> 16;
        int s6 = s8.w & 0xffff, s7 = s8.w >> 16;
        uint2 u0 = xh2[s0 * 16 + q];
        uint2 u1 = xh2[s1 * 16 + q];
        uint2 u2 = xh2[s2 * 16 + q];
        uint2 u3 = xh2[s3 * 16 + q];
        uint2 u4 = xh2[s4 * 16 + q];
        uint2 u5 = xh2[s5 * 16 + q];
        uint2 u6 = xh2[s6 * 16 + q];
        uint2 u7 = xh2[s7 * 16 + q];
        f4add(bf2f4(u0), acc); f4add(bf2f4(u1), acc);
        f4add(bf2f4(u2), acc); f4add(bf2f4(u3), acc);
        f4add(bf2f4(u4), acc); f4add(bf2f4(u5), acc);
        f4add(bf2f4(u6), acc); f4add(bf2f4(u7), acc);
    }
    for (; jj < c; ++jj) {
        uint2 u0 = xh2[cs[jj] * 16 + q];
        f4add(bf2f4(u0), acc);
    }
    f4add(bf2f4(xh2[node * 16 + q]), acc);   // self term (xh prescaled)
    float di = rsqrtf((float)(c + 1));
    acc.x *= di; acc.y *= di; acc.z *= di; acc.w *= di;
    ((uint2*)th)[node * 16 + q] = make_uint2(bfpack(acc.x, acc.y), bfpack(acc.z, acc.w));
}

// ---------- agg(bf16) = th @ W + BN stats: W in LDS, th direct from global ----------
// grid = 391 blocks x exactly 2 groups each (782 groups total)

__global__ __launch_bounds__(256) void k_gemm_stats(const unsigned short* __restrict__ th,
                                                    const float* __restrict__ W,
                                                    unsigned short* __restrict__ agg,
                                                    float* __restrict__ sums) {
    __shared__ float Wl[64 * 64];
    __shared__ float ls0[16][64];
    __shared__ float ls1[16][64];
    int tid = threadIdx.x;
    for (int i = tid; i < 64 * 64; i += 256) Wl[i] = W[i];
    __syncthreads();
    int sub = tid >> 4, q = tid & 15;
    const uint2* t2 = (const uint2*)th;
    const float4* W4 = (const float4*)Wl;
    uint2* agg2 = (uint2*)agg;
    float4 s1 = make_float4(0.f, 0.f, 0.f, 0.f), s2 = s1;
#pragma unroll
    for (int gg = 0; gg < 2; ++gg) {
        int g = blockIdx.x * 2 + gg;
        int n0 = g * 64 + sub * 4;
        int r0 = min(n0 + 0, NN - 1), r1 = min(n0 + 1, NN - 1);
        int r2 = min(n0 + 2, NN - 1), r3 = min(n0 + 3, NN - 1);
        float4 c0 = make_float4(0.f,0.f,0.f,0.f), c1 = c0, c2 = c0, c3 = c0;
#pragma unroll 4
        for (int k4 = 0; k4 < 16; ++k4) {
            float4 a0 = bf2f4(t2[r0 * 16 + k4]);
            float4 a1 = bf2f4(t2[r1 * 16 + k4]);
            float4 a2 = bf2f4(t2[r2 * 16 + k4]);
            float4 a3 = bf2f4(t2[r3 * 16 + k4]);
            float4 w0 = W4[(k4 * 4 + 0) * 16 + q];
            float4 w1 = W4[(k4 * 4 + 1) * 16 + q];
            float4 w2 = W4[(k4 * 4 + 2) * 16 + q];
            float4 w3 = W4[(k4 * 4 + 3) * 16 + q];
            f4fma(a0.x, w0, c0); f4fma(a0.y, w1, c0); f4fma(a0.z, w2, c0); f4fma(a0.w, w3, c0);
            f4fma(a1.x, w0, c1); f4fma(a1.y, w1, c1); f4fma(a1.z, w2, c1); f4fma(a1.w, w3, c1);
            f4fma(a2.x, w0, c2); f4fma(a2.y, w1, c2); f4fma(a2.z, w2, c2); f4fma(a2.w, w3, c2);
            f4fma(a3.x, w0, c3); f4fma(a3.y, w1, c3); f4fma(a3.z, w2, c3); f4fma(a3.w, w3, c3);
        }
        if (n0 + 0 < NN) { agg2[(n0 + 0) * 16 + q] = make_uint2(bfpack(c0.x, c0.y), bfpack(c0.z, c0.w));
            s1.x += c0.x; s1.y += c0.y; s1.z += c0.z; s1.w += c0.w;
            s2.x += c0.x*c0.x; s2.y += c0.y*c0.y; s2.z += c0.z*c0.z; s2.w += c0.w*c0.w; }
        if (n0 + 1 < NN) { agg2[(n0 + 1) * 16 + q] = make_uint2(bfpack(c1.x, c1.y), bfpack(c1.z, c1.w));
            s1.x += c1.x; s1.y += c1.y; s1.z += c1.z; s1.w += c1.w;
            s2.x += c1.x*c1.x; s2.y += c1.y*c1.y; s2.z += c1.z*c1.z; s2.w += c1.w*c1.w; }
        if (n0 + 2 < NN) { agg2[(n0 + 2) * 16 + q] = make_uint2(bfpack(c2.x, c2.y), bfpack(c2.z, c2.w));
            s1.x += c2.x; s1.y += c2.y; s1.z += c2.z; s1.w += c2.w;
            s2.x += c2.x*c2.x; s2.y += c2.y*c2.y; s2.z += c2.z*c2.z; s2.w += c2.w*c2.w; }
        if (n0 + 3 < NN) { agg2[(n0 + 3) * 16 + q] = make_uint2(bfpack(c3.x, c3.y), bfpack(c3.z, c3.w));
            s1.x += c3.x; s1.y += c3.y; s1.z += c3.z; s1.w += c3.w;
            s2.x += c3.x*c3.x; s2.y += c3.y*c3.y; s2.z += c3.z*c3.z; s2.w += c3.w*c3.w; }
    }
    ls0[sub][q * 4 + 0] = s1.x; ls0[sub][q * 4 + 1] = s1.y;
    ls0[sub][q * 4 + 2] = s1.z; ls0[sub][q * 4 + 3] = s1.w;
    ls1[sub][q * 4 + 0] = s2.x; ls1[sub][q * 4 + 1] = s2.y;
    ls1[sub][q * 4 + 2] = s2.z; ls1[sub][q * 4 + 3] = s2.w;
    __syncthreads();
    if (tid < 64) {
        float a = 0.f;
#pragma unroll
        for (int r = 0; r < 16; ++r) a += ls0[r][tid];
        atomicAdd(&sums[tid], a);
    } else if (tid < 128) {
        int c = tid - 64;
        float a = 0.f;
#pragma unroll
        for (int r = 0; r < 16; ++r) a += ls1[r][c];
        atomicAdd(&sums[64 + c], a);
    }
}

// ---------- x += relu(BN(agg)); refresh bf16 mirror ----------
// prescale==1: write x and prescaled xh (mid layer). prescale==0 (final): write ONLY xh (x dead).

__global__ __launch_bounds__(256) void k_bnupdate(const unsigned short* __restrict__ agg,
                                                  const float* __restrict__ sums,
                                                  const float* __restrict__ gamma,
                                                  const float* __restrict__ beta,
                                                  const int* __restrict__ cnt,
                                                  int prescale,
                                                  float* __restrict__ x,
                                                  unsigned short* __restrict__ xh) {
    int i = blockIdx.x * blockDim.x + threadIdx.x;
    if (i >= NN * 16) return;
    int f4 = i & 15;
    const float invn = 1.0f / (float)NN;
    float4 sm = ((const float4*)sums)[f4];
    float4 sq = ((const float4*)(sums + 64))[f4];
    float4 g = ((const float4*)gamma)[f4];
    float4 be = ((const float4*)beta)[f4];
    float4 a = bf2f4(((const uint2*)agg)[i]);
    float4 xv = ((const float4*)x)[i];
    float mu, var, rstd, xn;
    mu = sm.x * invn; var = sq.x * invn - mu * mu; rstd = rsqrtf(var + BN_EPS);
    xn = (a.x - mu) * rstd * g.x + be.x; xv.x += fmaxf(xn, 0.f);
    mu = sm.y * invn; var = sq.y * invn - mu * mu; rstd = rsqrtf(var + BN_EPS);
    xn = (a.y - mu) * rstd * g.y + be.y; xv.y += fmaxf(xn, 0.f);
    mu = sm.z * invn; var = sq.z * invn - mu * mu; rstd = rsqrtf(var + BN_EPS);
    xn = (a.z - mu) * rstd * g.z + be.z; xv.z += fmaxf(xn, 0.f);
    mu = sm.w * invn; var = sq.w * invn - mu * mu; rstd = rsqrtf(var + BN_EPS);
    xn = (a.w - mu) * rstd * g.w + be.w; xv.w += fmaxf(xn, 0.f);
    if (prescale) {
        ((float4*)x)[i] = xv;
        float d = rsqrtf((float)(cnt[i >> 4] + 1));
        ((uint2*)xh)[i] = make_uint2(bfpack(xv.x * d, xv.y * d), bfpack(xv.z * d, xv.w * d));
    } else {
        ((uint2*)xh)[i] = make_uint2(bfpack(xv.x, xv.y), bfpack(xv.z, xv.w));
    }
}

// ---------- decoder (bf16 rows, 4 edges/wave) ----------

__global__ __launch_bounds__(256) void k_decode(const int* __restrict__ pred,
                                                const unsigned short* __restrict__ zh,
                                                float* __restrict__ out) {
    int gw = (blockIdx.x * blockDim.x + threadIdx.x) >> 6;
    int lane = threadIdx.x & 63;
    int sub = lane >> 4, q = lane & 15;
    int p = gw * 4 + sub;
    if (p >= NP) return;
    const uint2* z2 = (const uint2*)zh;
    int a = pred[2 * p], b = pred[2 * p + 1];
    float4 va = bf2f4(z2[a * 16 + q]);
    float4 vb = bf2f4(z2[b * 16 + q]);
    float v = va.x * vb.x + va.y * vb.y + va.z * vb.z + va.w * vb.w;
    v += __shfl_xor(v, 1);
    v += __shfl_xor(v, 2);
    v += __shfl_xor(v, 4);
    v += __shfl_xor(v, 8);
    if (q == 0) out[p] = v;
}

extern "C" void kernel_launch(void* const* d_in, const int* in_sizes, int n_in,
                              void* d_out, int out_size, void* d_ws, size_t ws_size,
                              hipStream_t stream) {
    const int* edge_index = (const int*)d_in[0];   // [2][NE]
    const int* pred       = (const int*)d_in[1];   // [NP][2]
    const float* id_emb   = (const float*)d_in[2];
    const float* n2v      = (const float*)d_in[3];
    const float* proj_w   = (const float*)d_in[4];
    const float* proj_b   = (const float*)d_in[5];
    const float* conv_w   = (const float*)d_in[6]; // [2][64][64]
    // d_in[7] conv_b cancels inside BatchNorm -> skipped
    const float* gamma    = (const float*)d_in[8];
    const float* beta     = (const float*)d_in[9];
    float* out = (float*)d_out;

    char* ws = (char*)d_ws;
    size_t off = 0;
    int* cnt     = (int*)(ws + off);   off += alignup(NN * 4);
    unsigned char* rank = (unsigned char*)(ws + off); off += alignup((size_t)NE);
    unsigned short* csr = (unsigned short*)(ws + off); off += alignup((size_t)NN * MAXDEG * 2);
    float* x     = (float*)(ws + off); off += alignup((size_t)NN * 64 * 4);
    unsigned short* agg = (unsigned short*)(ws + off); off += alignup((size_t)NN * 64 * 2);
    unsigned short* xh = (unsigned short*)(ws + off); off += alignup((size_t)NN * 64 * 2);
    unsigned short* th = (unsigned short*)(ws + off); off += alignup((size_t)NN * 64 * 2);
    float* sums  = (float*)(ws + off); // 256 floats (2 layers x {sum,sumsq})

    const int* row = edge_index;
    const int* col = edge_index + NE;

    // CSR build (once, reused for both layers)
    k_zero<<<NB1, 256, 0, stream>>>(cnt, sums);
    k_count<<<(NE + 255) / 256, 256, 0, stream>>>(col, cnt, rank);
    k_fill<<<(NE + 255) / 256, 256, 0, stream>>>(row, col, rank, csr);

    k_proj<<<(NN + 31) / 32, 256, 0, stream>>>(id_emb, n2v, proj_w, proj_b, cnt, x, xh);

    for (int l = 0; l < 2; ++l) {
        k_gather<<<((NN + 3) / 4 * 64 + 255) / 256, 256, 0, stream>>>(cnt, csr, xh, th);
        k_gemm_stats<<<391, 256, 0, stream>>>(th, conv_w + l * 64 * 64, agg, sums + l * 128);
        k_bnupdate<<<(NN * 16 + 255) / 256, 256, 0, stream>>>(agg, sums + l * 128, gamma + l * 64,
                                                              beta + l * 64, cnt, (l == 0) ? 1 : 0, x, xh);
    }

    k_decode<<<(NP / 4 * 64 + 255) / 256, 256, 0, stream>>>(pred, xh, out);
}